// Round 2
// baseline (209.823 us; speedup 1.0000x reference)
//
#include <hip/hip_runtime.h>

#define NG 50000
#define NCT 64
#define NREF 16
#define NS 1024
#define N0 (NCT * NG)              // 3,200,000  (y0/y1/y2 length)

// d_out layout: out [NS*NG] | y0 [N0] | y1 [N0] | y2 [N0]
#define OFF_Y0 ((size_t)NS * NG)   // 51,200,000
#define OFF_Y1 (OFF_Y0 + N0)
#define OFF_Y2 (OFF_Y1 + N0)

// ---------------- Kernel 1: RefComb * tile + slice-sum -> y0 ----------------
// y0[j] = sum_{r<16} x[j*16+r] * w_ref[(j%64)*16 + r]
__global__ __launch_bounds__(256) void k_y0(const float* __restrict__ x,
                                            const float* __restrict__ w_ref,
                                            float* __restrict__ y0) {
    __shared__ float4 wl[256];                 // 1024 floats of w_ref
    const int tid = threadIdx.x;
    wl[tid] = reinterpret_cast<const float4*>(w_ref)[tid];
    __syncthreads();
    const int row = tid & 63;                  // j%64 == tid%64 (stride % 64 == 0)
    const float4 w0 = wl[row * 4 + 0];
    const float4 w1 = wl[row * 4 + 1];
    const float4 w2 = wl[row * 4 + 2];
    const float4 w3 = wl[row * 4 + 3];
    const float4* x4 = reinterpret_cast<const float4*>(x);
    const size_t stride = (size_t)gridDim.x * 256;
    for (size_t j = (size_t)blockIdx.x * 256 + tid; j < (size_t)N0; j += stride) {
        const float4* xp = x4 + j * 4;
        float4 a = xp[0], b = xp[1], c = xp[2], d = xp[3];
        float s = a.x * w0.x + a.y * w0.y + a.z * w0.z + a.w * w0.w
                + b.x * w1.x + b.y * w1.y + b.z * w1.z + b.w * w1.w
                + c.x * w2.x + c.y * w2.y + c.z * w2.z + c.w * w2.w
                + d.x * w3.x + d.y * w3.y + d.z * w3.z + d.w * w3.w;
        y0[j] = s;
    }
}

// ------------- Kernel 2: gather + celltype scale + stretch -> y1, y2 -------------
// y1[g*64+c] = y0[idx[c,g]] * w_ct[c];  y2 = y1 * w_stretch[g]
// Read side is c-major coalesced, write side g-major coalesced; transpose via LDS.
__global__ __launch_bounds__(256) void k_gather(const float* __restrict__ y0,
                                                const int* __restrict__ idx,
                                                const float* __restrict__ w_ct,
                                                const float* __restrict__ w_stretch,
                                                float* __restrict__ y1,
                                                float* __restrict__ y2) {
    __shared__ float T[64][65];                // +1 pad: conflict-free both phases
    const int tid = threadIdx.x;
    const int g0 = blockIdx.x * 64;
    // Phase A: c-major gather (idx reads coalesced)
#pragma unroll
    for (int k = 0; k < 16; ++k) {
        int lin = k * 256 + tid;
        int c = lin >> 6, gl = lin & 63;
        int g = g0 + gl;
        float t = 0.f;
        if (g < NG) t = y0[idx[c * NG + g]];
        T[c][gl] = t;
    }
    __syncthreads();
    // Phase B: g-major writes (coalesced)
#pragma unroll
    for (int k = 0; k < 16; ++k) {
        int lin = k * 256 + tid;
        int gl = lin >> 6, c = lin & 63;
        int g = g0 + gl;
        if (g < NG) {
            float t = T[c][gl];
            float v1 = t * w_ct[c];
            float v2 = v1 * w_stretch[g];
            size_t o = (size_t)g * 64 + c;
            y1[o] = v1;
            y2[o] = v2;
        }
    }
}

// ---------------- Kernel 3: K=64 GEMM  out[s,g] = sum_c y2[g,c]*cw[s,c] ----------------
// Tile: 64 genes x 128 samples per 256-thread block.
// Thread: 4 genes (gq*4) x 8 samples (sr*8) = 32 fp32 accumulators.
// LDS transposed [c][...] so compute reads are b128, broadcast/2-way (free).
__global__ __launch_bounds__(256) void k_conv(const float* __restrict__ y2,
                                              const float* __restrict__ cw,
                                              float* __restrict__ out) {
    __shared__ float Yl[64 * 68];              // [c][g], row stride 68 (16B-aligned)
    __shared__ float Wl[64 * 132];             // [c][s], row stride 132
    const int tid = threadIdx.x;
    const int g0 = blockIdx.x * 64;
    const int s0 = blockIdx.y * 128;

    // Load Y tile (64 genes x 64 c), transpose into Yl[c][g]
#pragma unroll
    for (int it = 0; it < 4; ++it) {
        int e0 = (it * 256 + tid) * 4;
        int gp = e0 >> 6;                      // 0..63
        int cp = e0 & 63;                      // multiple of 4
        float4 v = make_float4(0.f, 0.f, 0.f, 0.f);
        if (g0 + gp < NG) v = *reinterpret_cast<const float4*>(y2 + (size_t)(g0 + gp) * 64 + cp);
        Yl[(cp + 0) * 68 + gp] = v.x;
        Yl[(cp + 1) * 68 + gp] = v.y;
        Yl[(cp + 2) * 68 + gp] = v.z;
        Yl[(cp + 3) * 68 + gp] = v.w;
    }
    // Load W tile (128 samples x 64 c), transpose into Wl[c][s]
#pragma unroll
    for (int it = 0; it < 8; ++it) {
        int e0 = (it * 256 + tid) * 4;
        int sp = e0 >> 6;                      // 0..127
        int cp = e0 & 63;
        float4 v = *reinterpret_cast<const float4*>(cw + (size_t)(s0 + sp) * 64 + cp);
        Wl[(cp + 0) * 132 + sp] = v.x;
        Wl[(cp + 1) * 132 + sp] = v.y;
        Wl[(cp + 2) * 132 + sp] = v.z;
        Wl[(cp + 3) * 132 + sp] = v.w;
    }
    __syncthreads();

    const int gq4 = (tid & 15) * 4;            // local gene base (0..60)
    const int sr = tid >> 4;                   // 0..15 -> 8 samples each
    const int sr8 = sr * 8;

    float a0[8], a1[8], a2[8], a3[8];
#pragma unroll
    for (int j = 0; j < 8; ++j) { a0[j] = a1[j] = a2[j] = a3[j] = 0.f; }

#pragma unroll 16
    for (int c = 0; c < 64; ++c) {
        float4 yv = *reinterpret_cast<const float4*>(&Yl[c * 68 + gq4]);
        float4 wA = *reinterpret_cast<const float4*>(&Wl[c * 132 + sr8]);
        float4 wB = *reinterpret_cast<const float4*>(&Wl[c * 132 + sr8 + 4]);
        float wv[8] = {wA.x, wA.y, wA.z, wA.w, wB.x, wB.y, wB.z, wB.w};
#pragma unroll
        for (int j = 0; j < 8; ++j) {
            a0[j] += yv.x * wv[j];
            a1[j] += yv.y * wv[j];
            a2[j] += yv.z * wv[j];
            a3[j] += yv.w * wv[j];
        }
    }

    const int gg = g0 + gq4;
    if (gg < NG) {
#pragma unroll
        for (int j = 0; j < 8; ++j) {
            int s = s0 + sr8 + j;
            float4 v = make_float4(a0[j], a1[j], a2[j], a3[j]);
            *reinterpret_cast<float4*>(out + (size_t)s * NG + gg) = v;
        }
    }
}

extern "C" void kernel_launch(void* const* d_in, const int* in_sizes, int n_in,
                              void* d_out, int out_size, void* d_ws, size_t ws_size,
                              hipStream_t stream) {
    const float* x         = (const float*)d_in[0];
    const int*   idx       = (const int*)d_in[1];
    const float* w_ref     = (const float*)d_in[2];
    const float* w_ct      = (const float*)d_in[3];
    const float* w_stretch = (const float*)d_in[4];
    const float* conv_w    = (const float*)d_in[5];

    float* out = (float*)d_out;
    float* y0  = out + OFF_Y0;
    float* y1  = out + OFF_Y1;
    float* y2  = out + OFF_Y2;

    k_y0<<<2048, 256, 0, stream>>>(x, w_ref, y0);
    k_gather<<<(NG + 63) / 64, 256, 0, stream>>>(y0, idx, w_ct, w_stretch, y1, y2);
    k_conv<<<dim3((NG + 63) / 64, NS / 128), 256, 0, stream>>>(y2, conv_w, out);
}

// Round 7
// 184.851 us; speedup vs baseline: 1.1351x; 1.1351x over previous
//
#include <hip/hip_runtime.h>

#define NG 50000
#define NCT 64
#define NREF 16
#define NS 1024
#define N0 (NCT * NG)              // 3,200,000  (y0/y1/y2 length)

// d_out layout: out [NS*NG] | y0 [N0] | y1 [N0] | y2 [N0]
#define OFF_Y0 ((size_t)NS * NG)   // 51,200,000
#define OFF_Y1 (OFF_Y0 + N0)
#define OFF_Y2 (OFF_Y1 + N0)

typedef __attribute__((ext_vector_type(8))) short bf16x8;
typedef __attribute__((ext_vector_type(4))) float f32x4;

__device__ __forceinline__ unsigned short f2bf(float f) {
    union { float f; unsigned u; } v; v.f = f;
    unsigned r = v.u + 0x7fff + ((v.u >> 16) & 1);   // RNE
    return (unsigned short)(r >> 16);
}
__device__ __forceinline__ float bf2f(unsigned short b) {
    union { float f; unsigned u; } v; v.u = ((unsigned)b) << 16;
    return v.f;
}

// ---------------- Kernel 1: RefComb * tile + slice-sum -> y0 ----------------
// y0[j] = sum_{r<16} x[j*16+r] * w_ref[(j%64)*16 + r]
__global__ __launch_bounds__(256) void k_y0(const float* __restrict__ x,
                                            const float* __restrict__ w_ref,
                                            float* __restrict__ y0) {
    __shared__ float4 wl[256];                 // 1024 floats of w_ref
    const int tid = threadIdx.x;
    wl[tid] = reinterpret_cast<const float4*>(w_ref)[tid];
    __syncthreads();
    const int row = tid & 63;                  // j%64 == tid%64 (stride % 64 == 0)
    const float4 w0 = wl[row * 4 + 0];
    const float4 w1 = wl[row * 4 + 1];
    const float4 w2 = wl[row * 4 + 2];
    const float4 w3 = wl[row * 4 + 3];
    const float4* x4 = reinterpret_cast<const float4*>(x);
    const size_t stride = (size_t)gridDim.x * 256;
    for (size_t j = (size_t)blockIdx.x * 256 + tid; j < (size_t)N0; j += stride) {
        const float4* xp = x4 + j * 4;
        float4 a = xp[0], b = xp[1], c = xp[2], d = xp[3];
        float s = a.x * w0.x + a.y * w0.y + a.z * w0.z + a.w * w0.w
                + b.x * w1.x + b.y * w1.y + b.z * w1.z + b.w * w1.w
                + c.x * w2.x + c.y * w2.y + c.z * w2.z + c.w * w2.w
                + d.x * w3.x + d.y * w3.y + d.z * w3.z + d.w * w3.w;
        y0[j] = s;
    }
}

// ------------- Kernel 2: gather + celltype scale + stretch -> y1, y2 -------------
__global__ __launch_bounds__(256) void k_gather(const float* __restrict__ y0,
                                                const int* __restrict__ idx,
                                                const float* __restrict__ w_ct,
                                                const float* __restrict__ w_stretch,
                                                float* __restrict__ y1,
                                                float* __restrict__ y2) {
    __shared__ float T[64][65];                // +1 pad: conflict-free both phases
    const int tid = threadIdx.x;
    const int g0 = blockIdx.x * 64;
    // Phase A: c-major gather (idx reads coalesced)
#pragma unroll
    for (int k = 0; k < 16; ++k) {
        int lin = k * 256 + tid;
        int c = lin >> 6, gl = lin & 63;
        int g = g0 + gl;
        float t = 0.f;
        if (g < NG) t = y0[idx[c * NG + g]];
        T[c][gl] = t;
    }
    __syncthreads();
    // Phase B: g-major writes (coalesced)
#pragma unroll
    for (int k = 0; k < 16; ++k) {
        int lin = k * 256 + tid;
        int gl = lin >> 6, c = lin & 63;
        int g = g0 + gl;
        if (g < NG) {
            float t = T[c][gl];
            float v1 = t * w_ct[c];
            float v2 = v1 * w_stretch[g];
            size_t o = (size_t)g * 64 + c;
            y1[o] = v1;
            y2[o] = v2;
        }
    }
}

// ---------------- Kernel 3: MFMA conv  out[s,g] = sum_c y2[g,c]*cw[s,c] ----------------
// A = y2 tile (M=g x K=c), B = cw^T (K=c x N=s), D[g,s].
// Split each fp32 operand into hi+lo bf16; acc += Ah*Bh + Ah*Bl + Al*Bh (fp32 MFMA acc).
// Tile: 64 genes x 128 samples, 256 threads (4 waves), wave owns 32 samples.
// D layout (m89-verified): col = lane&15 -> s, row = (lane>>4)*4+reg -> g (4 consecutive
// genes per lane => float4 stores, g-contiguous).
#define STILE 128
__global__ __launch_bounds__(256) void k_conv(const float* __restrict__ y2,
                                              const float* __restrict__ cw,
                                              float* __restrict__ out) {
    __shared__ unsigned short Yhi[64 * 72];    // [g][c], pad to 72 (2-way bank alias = free)
    __shared__ unsigned short Ylo[64 * 72];
    __shared__ unsigned short Whi[STILE * 72]; // [s][c]
    __shared__ unsigned short Wlo[STILE * 72];
    const int tid = threadIdx.x;
    const int g0 = blockIdx.x * 64;
    const int s0 = blockIdx.y * STILE;

    // Load y2 tile (64 g x 64 c fp32), convert to hi/lo bf16
#pragma unroll
    for (int it = 0; it < 4; ++it) {
        int e0 = (it * 256 + tid) * 4;
        int gp = e0 >> 6;                      // 0..63
        int cp = e0 & 63;                      // multiple of 4
        float4 v = make_float4(0.f, 0.f, 0.f, 0.f);
        if (g0 + gp < NG) v = *reinterpret_cast<const float4*>(y2 + (size_t)(g0 + gp) * 64 + cp);
        unsigned short h0 = f2bf(v.x), h1 = f2bf(v.y), h2 = f2bf(v.z), h3 = f2bf(v.w);
        int base = gp * 72 + cp;
        Yhi[base + 0] = h0; Yhi[base + 1] = h1; Yhi[base + 2] = h2; Yhi[base + 3] = h3;
        Ylo[base + 0] = f2bf(v.x - bf2f(h0));
        Ylo[base + 1] = f2bf(v.y - bf2f(h1));
        Ylo[base + 2] = f2bf(v.z - bf2f(h2));
        Ylo[base + 3] = f2bf(v.w - bf2f(h3));
    }
    // Load cw tile (STILE s x 64 c fp32), convert to hi/lo bf16
#pragma unroll
    for (int it = 0; it < 8; ++it) {
        int e0 = (it * 256 + tid) * 4;
        int sp = e0 >> 6;                      // 0..STILE-1
        int cp = e0 & 63;
        float4 v = *reinterpret_cast<const float4*>(cw + (size_t)(s0 + sp) * 64 + cp);
        unsigned short h0 = f2bf(v.x), h1 = f2bf(v.y), h2 = f2bf(v.z), h3 = f2bf(v.w);
        int base = sp * 72 + cp;
        Whi[base + 0] = h0; Whi[base + 1] = h1; Whi[base + 2] = h2; Whi[base + 3] = h3;
        Wlo[base + 0] = f2bf(v.x - bf2f(h0));
        Wlo[base + 1] = f2bf(v.y - bf2f(h1));
        Wlo[base + 2] = f2bf(v.z - bf2f(h2));
        Wlo[base + 3] = f2bf(v.w - bf2f(h3));
    }
    __syncthreads();

    const int lane = tid & 63;
    const int wid  = tid >> 6;                 // 0..3
    const int l15  = lane & 15;
    const int l4   = lane >> 4;                // 0..3
    const int nb   = wid * 32;                 // wave's local s base

    // B fragments: 2 n-frags x 2 k-steps x {hi,lo}
    bf16x8 Bh[2][2], Bl[2][2];
#pragma unroll
    for (int n = 0; n < 2; ++n) {
        int srow = nb + n * 16 + l15;
#pragma unroll
        for (int ks = 0; ks < 2; ++ks) {
            int koff = ks * 32 + l4 * 8;
            Bh[n][ks] = *reinterpret_cast<const bf16x8*>(&Whi[srow * 72 + koff]);
            Bl[n][ks] = *reinterpret_cast<const bf16x8*>(&Wlo[srow * 72 + koff]);
        }
    }

    f32x4 acc[4][2];
#pragma unroll
    for (int m = 0; m < 4; ++m)
#pragma unroll
        for (int n = 0; n < 2; ++n) acc[m][n] = (f32x4){0.f, 0.f, 0.f, 0.f};

#pragma unroll
    for (int m = 0; m < 4; ++m) {
        int grow = m * 16 + l15;
        bf16x8 Ah[2], Al[2];
#pragma unroll
        for (int ks = 0; ks < 2; ++ks) {
            int koff = ks * 32 + l4 * 8;
            Ah[ks] = *reinterpret_cast<const bf16x8*>(&Yhi[grow * 72 + koff]);
            Al[ks] = *reinterpret_cast<const bf16x8*>(&Ylo[grow * 72 + koff]);
        }
#pragma unroll
        for (int n = 0; n < 2; ++n) {
#pragma unroll
            for (int ks = 0; ks < 2; ++ks) {
                acc[m][n] = __builtin_amdgcn_mfma_f32_16x16x32_bf16(Ah[ks], Bh[n][ks], acc[m][n], 0, 0, 0);
                acc[m][n] = __builtin_amdgcn_mfma_f32_16x16x32_bf16(Ah[ks], Bl[n][ks], acc[m][n], 0, 0, 0);
                acc[m][n] = __builtin_amdgcn_mfma_f32_16x16x32_bf16(Al[ks], Bh[n][ks], acc[m][n], 0, 0, 0);
            }
        }
    }

    // Store: lane's 4 regs = 4 consecutive genes => float4
#pragma unroll
    for (int m = 0; m < 4; ++m) {
        int g4 = g0 + m * 16 + l4 * 4;
        if (g4 < NG) {
#pragma unroll
            for (int n = 0; n < 2; ++n) {
                int s = s0 + nb + n * 16 + l15;
                *reinterpret_cast<f32x4*>(out + (size_t)s * NG + g4) = acc[m][n];
            }
        }
    }
}

extern "C" void kernel_launch(void* const* d_in, const int* in_sizes, int n_in,
                              void* d_out, int out_size, void* d_ws, size_t ws_size,
                              hipStream_t stream) {
    const float* x         = (const float*)d_in[0];
    const int*   idx       = (const int*)d_in[1];
    const float* w_ref     = (const float*)d_in[2];
    const float* w_ct      = (const float*)d_in[3];
    const float* w_stretch = (const float*)d_in[4];
    const float* conv_w    = (const float*)d_in[5];

    float* out = (float*)d_out;
    float* y0  = out + OFF_Y0;
    float* y1  = out + OFF_Y1;
    float* y2  = out + OFF_Y2;

    k_y0<<<2048, 256, 0, stream>>>(x, w_ref, y0);
    k_gather<<<(NG + 63) / 64, 256, 0, stream>>>(y0, idx, w_ct, w_stretch, y1, y2);
    k_conv<<<dim3((NG + 63) / 64, NS / STILE), 256, 0, stream>>>(y2, conv_w, out);
}

// Round 9
// 180.187 us; speedup vs baseline: 1.1645x; 1.0259x over previous
//
#include <hip/hip_runtime.h>

#define NG 50000
#define NCT 64
#define NREF 16
#define NS 1024
#define N0 (NCT * NG)              // 3,200,000  (y0/y1/y2 length)

// d_out layout: out [NS*NG] | y0 [N0] | y1 [N0] | y2 [N0]
#define OFF_Y0 ((size_t)NS * NG)   // 51,200,000
#define OFF_Y1 (OFF_Y0 + N0)
#define OFF_Y2 (OFF_Y1 + N0)

typedef __attribute__((ext_vector_type(8))) short bf16x8;
typedef __attribute__((ext_vector_type(4))) float f32x4;

__device__ __forceinline__ unsigned short f2bf(float f) {
    union { float f; unsigned u; } v; v.f = f;
    unsigned r = v.u + 0x7fff + ((v.u >> 16) & 1);   // RNE
    return (unsigned short)(r >> 16);
}
__device__ __forceinline__ float bf2f(unsigned short b) {
    union { float f; unsigned u; } v; v.u = ((unsigned)b) << 16;
    return v.f;
}

// ---------------- Kernel 1: RefComb * tile + slice-sum -> y0 ----------------
// y0[j] = sum_{r<16} x[j*16+r] * w_ref[(j%64)*16 + r]
__global__ __launch_bounds__(256) void k_y0(const float* __restrict__ x,
                                            const float* __restrict__ w_ref,
                                            float* __restrict__ y0) {
    __shared__ f32x4 wl[256];                  // 1024 floats of w_ref
    const int tid = threadIdx.x;
    wl[tid] = reinterpret_cast<const f32x4*>(w_ref)[tid];
    __syncthreads();
    const int row = tid & 63;                  // j%64 == tid%64 (stride % 64 == 0)
    const f32x4 w0 = wl[row * 4 + 0];
    const f32x4 w1 = wl[row * 4 + 1];
    const f32x4 w2 = wl[row * 4 + 2];
    const f32x4 w3 = wl[row * 4 + 3];
    const f32x4* x4 = reinterpret_cast<const f32x4*>(x);
    const size_t stride = (size_t)gridDim.x * 256;
    for (size_t j = (size_t)blockIdx.x * 256 + tid; j < (size_t)N0; j += stride) {
        const f32x4* xp = x4 + j * 4;
        f32x4 a = __builtin_nontemporal_load(xp + 0);
        f32x4 b = __builtin_nontemporal_load(xp + 1);
        f32x4 c = __builtin_nontemporal_load(xp + 2);
        f32x4 d = __builtin_nontemporal_load(xp + 3);
        float s = a.x * w0.x + a.y * w0.y + a.z * w0.z + a.w * w0.w
                + b.x * w1.x + b.y * w1.y + b.z * w1.z + b.w * w1.w
                + c.x * w2.x + c.y * w2.y + c.z * w2.z + c.w * w2.w
                + d.x * w3.x + d.y * w3.y + d.z * w3.z + d.w * w3.w;
        y0[j] = s;                             // cached store: gather re-reads y0
    }
}

// ------- Kernel 2 (fused): gather + scale + stretch + MFMA conv -------
// Per 64-gene block:
//   Phase A: 16-deep pipelined random gather (idx c-major coalesced) -> T[c][g] LDS
//   Phase B: y1/y2 NT-stores (g-major coalesced) + build hi/lo bf16 A-tile [g][c]
//   Chunk loop (8x): stage cw[s-chunk] hi/lo into LDS (overlays dead T), MFMA, NT-store out
// MFMA: A = y2-tile (M=g,K=c), B = cw^T (K=c,N=s); split fp32 = hi+lo bf16,
// acc += Ah*Bh + Ah*Bl + Al*Bh. D layout (m89): col=lane&15 -> s, row=(lane>>4)*4+reg -> g.
#define STILE 128
__global__ __launch_bounds__(256) void k_fused(const float* __restrict__ y0,
                                               const int* __restrict__ idx,
                                               const float* __restrict__ w_ct,
                                               const float* __restrict__ w_stretch,
                                               const float* __restrict__ cw,
                                               float* __restrict__ y1,
                                               float* __restrict__ y2,
                                               float* __restrict__ out) {
    __shared__ unsigned short Yhi[64 * 72];          // [g][c] A-tile hi (9216 B)
    __shared__ unsigned short Ylo[64 * 72];          // [g][c] A-tile lo (9216 B)
    __shared__ char Rbuf[2 * STILE * 72 * 2];        // 36864 B: T (16640 B) then Whi|Wlo
    float* T = reinterpret_cast<float*>(Rbuf);       // [64][65] gather tile (c-major)
    unsigned short* Whi = reinterpret_cast<unsigned short*>(Rbuf);
    unsigned short* Wlo = Whi + STILE * 72;

    const int tid = threadIdx.x;
    const int g0 = blockIdx.x * 64;

    // ---- Phase A: gather, 16-deep MLP (ids then vals) ----
    int ids[16];
#pragma unroll
    for (int k = 0; k < 16; ++k) {
        int lin = k * 256 + tid;
        int c = lin >> 6, gl = lin & 63;
        int gc = min(g0 + gl, NG - 1);               // clamp; garbage rows masked at stores
        ids[k] = idx[c * NG + gc];
    }
    float vals[16];
#pragma unroll
    for (int k = 0; k < 16; ++k) vals[k] = y0[ids[k]];
#pragma unroll
    for (int k = 0; k < 16; ++k) {
        int lin = k * 256 + tid;
        int c = lin >> 6, gl = lin & 63;
        T[c * 65 + gl] = vals[k];
    }
    __syncthreads();

    // ---- Phase B: y1/y2 out + hi/lo A-tile ----
#pragma unroll
    for (int k = 0; k < 16; ++k) {
        int lin = k * 256 + tid;
        int gl = lin >> 6, c = lin & 63;             // gl wave-uniform per k
        int g = g0 + gl;
        float t = T[c * 65 + gl];                    // (c+gl)%32 banks: 2-way, free
        float v1 = t * w_ct[c];
        float v2 = v1 * w_stretch[min(g, NG - 1)];   // wave-uniform scalar load
        int base = gl * 72 + c;
        unsigned short h = f2bf(v2);
        Yhi[base] = h;
        Ylo[base] = f2bf(v2 - bf2f(h));
        if (g < NG) {
            size_t o = (size_t)g * 64 + c;
            __builtin_nontemporal_store(v1, y1 + o);
            __builtin_nontemporal_store(v2, y2 + o);
        }
    }
    __syncthreads();                                 // T dead after this point

    const int lane = tid & 63;
    const int wid  = tid >> 6;                       // 0..3
    const int l15  = lane & 15;
    const int l4   = lane >> 4;                      // 0..3
    const int nb   = wid * 32;                       // wave's local s base

    // A fragments: loaded ONCE per block (was 8x per gene in unfused version)
    bf16x8 Ah[4][2], Al[4][2];
#pragma unroll
    for (int m = 0; m < 4; ++m) {
        int grow = m * 16 + l15;
#pragma unroll
        for (int ks = 0; ks < 2; ++ks) {
            int koff = ks * 32 + l4 * 8;
            Ah[m][ks] = *reinterpret_cast<const bf16x8*>(&Yhi[grow * 72 + koff]);
            Al[m][ks] = *reinterpret_cast<const bf16x8*>(&Ylo[grow * 72 + koff]);
        }
    }

    // ---- Chunk loop over samples ----
    for (int s0 = 0; s0 < NS; s0 += STILE) {
        // stage cw chunk (STILE x 64 fp32 -> hi/lo), overlays dead T
#pragma unroll
        for (int it = 0; it < 8; ++it) {
            int e0 = (it * 256 + tid) * 4;
            int sp = e0 >> 6;                        // 0..STILE-1
            int cp = e0 & 63;
            f32x4 v = *reinterpret_cast<const f32x4*>(cw + (size_t)(s0 + sp) * 64 + cp);
            unsigned short h0 = f2bf(v.x), h1 = f2bf(v.y), h2 = f2bf(v.z), h3 = f2bf(v.w);
            int base = sp * 72 + cp;
            Whi[base + 0] = h0; Whi[base + 1] = h1; Whi[base + 2] = h2; Whi[base + 3] = h3;
            Wlo[base + 0] = f2bf(v.x - bf2f(h0));
            Wlo[base + 1] = f2bf(v.y - bf2f(h1));
            Wlo[base + 2] = f2bf(v.z - bf2f(h2));
            Wlo[base + 3] = f2bf(v.w - bf2f(h3));
        }
        __syncthreads();

        bf16x8 Bh[2][2], Bl[2][2];
#pragma unroll
        for (int n = 0; n < 2; ++n) {
            int srow = nb + n * 16 + l15;
#pragma unroll
            for (int ks = 0; ks < 2; ++ks) {
                int koff = ks * 32 + l4 * 8;
                Bh[n][ks] = *reinterpret_cast<const bf16x8*>(&Whi[srow * 72 + koff]);
                Bl[n][ks] = *reinterpret_cast<const bf16x8*>(&Wlo[srow * 72 + koff]);
            }
        }

        f32x4 acc[4][2];
#pragma unroll
        for (int m = 0; m < 4; ++m)
#pragma unroll
            for (int n = 0; n < 2; ++n) acc[m][n] = (f32x4){0.f, 0.f, 0.f, 0.f};

#pragma unroll
        for (int m = 0; m < 4; ++m)
#pragma unroll
            for (int n = 0; n < 2; ++n)
#pragma unroll
                for (int ks = 0; ks < 2; ++ks) {
                    acc[m][n] = __builtin_amdgcn_mfma_f32_16x16x32_bf16(Ah[m][ks], Bh[n][ks], acc[m][n], 0, 0, 0);
                    acc[m][n] = __builtin_amdgcn_mfma_f32_16x16x32_bf16(Ah[m][ks], Bl[n][ks], acc[m][n], 0, 0, 0);
                    acc[m][n] = __builtin_amdgcn_mfma_f32_16x16x32_bf16(Al[m][ks], Bh[n][ks], acc[m][n], 0, 0, 0);
                }

        // NT stores: lane's 4 regs = 4 consecutive genes => f32x4
#pragma unroll
        for (int m = 0; m < 4; ++m) {
            int g4 = g0 + m * 16 + l4 * 4;
            if (g4 < NG) {
#pragma unroll
                for (int n = 0; n < 2; ++n) {
                    int s = s0 + nb + n * 16 + l15;
                    __builtin_nontemporal_store(acc[m][n], reinterpret_cast<f32x4*>(out + (size_t)s * NG + g4));
                }
            }
        }
        __syncthreads();                             // drain before next W overwrite
    }
}

extern "C" void kernel_launch(void* const* d_in, const int* in_sizes, int n_in,
                              void* d_out, int out_size, void* d_ws, size_t ws_size,
                              hipStream_t stream) {
    const float* x         = (const float*)d_in[0];
    const int*   idx       = (const int*)d_in[1];
    const float* w_ref     = (const float*)d_in[2];
    const float* w_ct      = (const float*)d_in[3];
    const float* w_stretch = (const float*)d_in[4];
    const float* conv_w    = (const float*)d_in[5];

    float* out = (float*)d_out;
    float* y0  = out + OFF_Y0;
    float* y1  = out + OFF_Y1;
    float* y2  = out + OFF_Y2;

    k_y0<<<2048, 256, 0, stream>>>(x, w_ref, y0);
    k_fused<<<(NG + 63) / 64, 256, 0, stream>>>(y0, idx, w_ct, w_stretch, conv_w, y1, y2, out);
}